// Round 7
// baseline (260.132 us; speedup 1.0000x reference)
//
#include <hip/hip_runtime.h>
#include <hip/hip_bf16.h>
#include <cstdint>

#define D 128
#define LDSPITCH 136   // shorts; 272B row stride: 16B-aligned, banks uniform
#define CAP 32         // bucket capacity/row (Poisson(6): P(>32) ~ 1e-13)

typedef __attribute__((ext_vector_type(4))) float f32x4;
typedef __attribute__((ext_vector_type(8))) short s16x8;

__device__ __forceinline__ unsigned short f2b(float f) {
    union { float f; uint32_t u; } v; v.f = f;
    uint32_t b = v.u + 0x7fffu + ((v.u >> 16) & 1u);   // RNE
    return (unsigned short)(b >> 16);
}
__device__ __forceinline__ float b2f(unsigned short u) {
    union { uint32_t u; float f; } v; v.u = ((uint32_t)u) << 16; return v.f;
}

// ---- prep: [0,192) transpose+bf16 weights; 192: consts + zero xb sentinel row;
//            [193,193+zb): zero cursor; [193+zb,..): fill srcs with sentinel N
__global__ __launch_bounds__(256) void k_prep(
    const float* __restrict__ fp_w, const float* __restrict__ lin_l_w,
    const float* __restrict__ lin_r_w,
    unsigned short* __restrict__ Btf, unsigned short* __restrict__ Btl,
    unsigned short* __restrict__ Btr,
    const float* __restrict__ res_w, const float* __restrict__ res_b,
    const float* __restrict__ sh_w, const float* __restrict__ sh_b,
    const float* __restrict__ alpha, float* __restrict__ c1, float* __restrict__ scal,
    int* __restrict__ cursor, int* __restrict__ srcs, unsigned short* __restrict__ xb,
    int N, int zb) {
    int bid = blockIdx.x, tid = threadIdx.x;
    if (bid < 192) {
        int m = bid >> 6;
        int i = (bid & 63) * 256 + tid;
        const float* src = (m == 0) ? fp_w : (m == 1) ? lin_l_w : lin_r_w;
        unsigned short* dst = (m == 0) ? Btf : (m == 1) ? Btl : Btr;
        int k = i >> 7, n = i & 127;
        dst[n * D + k] = f2b(src[k * D + n]);
    } else if (bid == 192) {
        if (tid < 128) {
            float s = 0.f;
            for (int j = 0; j < D; ++j) s += res_w[tid * D + j] * sh_w[j];
            c1[tid] = s;
            if (tid == 0) {
                float c0 = 0.f;
                for (int j = 0; j < D; ++j) c0 += res_b[j] * sh_w[j];
                c0 += sh_b[0];
                float a = 1.f / (1.f + expf(-alpha[0]));
                scal[0] = a; scal[1] = c0;
            }
        } else if (tid < 192) {
            // zero the sentinel row N of xb (128 shorts = 64 uints)
            ((unsigned int*)(xb + (size_t)N * D))[tid - 128] = 0u;
        }
    } else if (bid < 193 + zb) {
        int i = ((bid - 193) * 256 + tid) * 4;
        if (i < N) {
            if (i + 3 < N) *(int4*)(cursor + i) = (int4){0, 0, 0, 0};
            else { for (int k = i; k < N; ++k) cursor[k] = 0; }
        }
    } else {
        int i = ((bid - 193 - zb) * 256 + tid) * 4;
        if (i < N * CAP) *(int4*)(srcs + i) = (int4){N, N, N, N};
    }
}

// ---- GEMM1 (+ bucket fill piggy-backed):
// blocks [0,mb): xf = [x|pos|len] @ fp_w + fp_b -> bf16 xb; d1 = xf.c1
// blocks [mb,..): cursor[dst]++ + srcs[dst*CAP+pos] = src
__global__ __launch_bounds__(256) void k_gemm1(
    const float* __restrict__ x, unsigned short* __restrict__ xb,
    const int* __restrict__ positions, const int* __restrict__ lengths,
    const unsigned short* __restrict__ Btf,
    const float* __restrict__ fp_w, const float* __restrict__ fp_b,
    const float* __restrict__ c1, float* __restrict__ d1, int N, int mb,
    const int* __restrict__ ei, int* __restrict__ cursor, int* __restrict__ srcs, int E) {
    if (blockIdx.x >= mb) {
        int e = (blockIdx.x - mb) * 256 + threadIdx.x;
        if (e < E) {
            int src = ei[e];
            int dst = ei[E + e];
            int pos = atomicAdd(&cursor[dst], 1);
            if (pos < CAP) srcs[dst * CAP + pos] = src;
        }
        return;
    }
    int lane = threadIdx.x & 63;
    int wv = threadIdx.x >> 6;
    int col = lane & 15, q = lane >> 4;
    int row0 = blockIdx.x * 64 + wv * 16;
    int arow = row0 + col; if (arow > N - 1) arow = N - 1;

    f32x4 acc[8];
#pragma unroll
    for (int nt = 0; nt < 8; ++nt) acc[nt] = (f32x4){0.f, 0.f, 0.f, 0.f};

#pragma unroll
    for (int ks = 0; ks < 4; ++ks) {
        const float* xp = x + (size_t)arow * D + ks * 32 + q * 8;
        float4 a0 = *(const float4*)xp;
        float4 a1 = *(const float4*)(xp + 4);
        s16x8 af;
        af[0] = (short)f2b(a0.x); af[1] = (short)f2b(a0.y);
        af[2] = (short)f2b(a0.z); af[3] = (short)f2b(a0.w);
        af[4] = (short)f2b(a1.x); af[5] = (short)f2b(a1.y);
        af[6] = (short)f2b(a1.z); af[7] = (short)f2b(a1.w);
#pragma unroll
        for (int nt = 0; nt < 8; ++nt) {
            s16x8 bf = *(const s16x8*)(Btf + (size_t)(nt * 16 + col) * D + ks * 32 + q * 8);
            acc[nt] = __builtin_amdgcn_mfma_f32_16x16x32_bf16(af, bf, acc[nt], 0, 0, 0);
        }
    }

    float pf[4], lf[4];
#pragma unroll
    for (int r = 0; r < 4; ++r) {
        int rr = row0 + q * 4 + r; int rc = rr < N ? rr : N - 1;
        pf[r] = (float)positions[rc] * (1.0f / 50.0f);
        lf[r] = (float)lengths[rc] * (1.0f / 500.0f);
    }
    float sdot[4] = {0.f, 0.f, 0.f, 0.f};
#pragma unroll
    for (int nt = 0; nt < 8; ++nt) {
        int n = nt * 16 + col;
        float bias = fp_b[n];
        float w128 = fp_w[128 * D + n];
        float w129 = fp_w[129 * D + n];
        float c1v = c1[n];
#pragma unroll
        for (int r = 0; r < 4; ++r) {
            float t = acc[nt][r] + bias + pf[r] * w128 + lf[r] * w129;
            int rr = row0 + q * 4 + r;
            if (rr < N) xb[(size_t)rr * D + n] = f2b(t);
            sdot[r] += t * c1v;
        }
    }
#pragma unroll
    for (int r = 0; r < 4; ++r) {
        float s = sdot[r];
        s += __shfl_xor(s, 1, 64);
        s += __shfl_xor(s, 2, 64);
        s += __shfl_xor(s, 4, 64);
        s += __shfl_xor(s, 8, 64);
        if (col == 0) {
            int rr = row0 + q * 4 + r;
            if (rr < N) d1[rr] = s;
        }
    }
}

// ---- GEMM2 fused with bucket mean-gather.
// Uniform-round gather: sentinel-padded buckets (unused slots -> zero row N),
// wave-max round count, straight-line unrolled body (4 rows x 8 gathers/round).
__global__ __launch_bounds__(256) void k_gemm2(
    const unsigned short* __restrict__ xfb,
    const int* __restrict__ cursor, const int* __restrict__ srcs,
    const unsigned short* __restrict__ Btl, const unsigned short* __restrict__ Btr,
    const float* __restrict__ lin_l_b, const float* __restrict__ sh_w,
    const float* __restrict__ rer, const float* __restrict__ d1,
    const float* __restrict__ scal, float* __restrict__ out, int N) {
    __shared__ unsigned short agg[64 * LDSPITCH];
    int lane = threadIdx.x & 63;
    int wv = threadIdx.x >> 6;
    int li = lane & 15, q = lane >> 4;
    int wrow0 = blockIdx.x * 64 + wv * 16;

    int degs[4];
    const int* sp[4];
#pragma unroll
    for (int rr = 0; rr < 4; ++rr) {
        int row = wrow0 + rr * 4 + q;
        int ok = row < N;
        int dg = ok ? cursor[row] : 0;
        degs[rr] = dg > CAP ? CAP : dg;
        sp[rr] = srcs + (size_t)(ok ? row : 0) * CAP;
    }
    int dmax = degs[0] > degs[1] ? degs[0] : degs[1];
    if (degs[2] > dmax) dmax = degs[2];
    if (degs[3] > dmax) dmax = degs[3];
    dmax = max(dmax, __shfl_xor(dmax, 16, 64));
    dmax = max(dmax, __shfl_xor(dmax, 32, 64));
    int rounds = (dmax + 7) >> 3;

    float t[4][8];
#pragma unroll
    for (int rr = 0; rr < 4; ++rr)
#pragma unroll
        for (int k2 = 0; k2 < 8; ++k2) t[rr][k2] = 0.f;

    for (int jr = 0; jr < rounds; ++jr) {
        int j = jr * 8;
#pragma unroll
        for (int rr = 0; rr < 4; ++rr) {
            int4 ia = *(const int4*)(sp[rr] + j);
            int4 ib = *(const int4*)(sp[rr] + j + 4);
            s16x8 v0 = *(const s16x8*)(xfb + (size_t)ia.x * D + li * 8);
            s16x8 v1 = *(const s16x8*)(xfb + (size_t)ia.y * D + li * 8);
            s16x8 v2 = *(const s16x8*)(xfb + (size_t)ia.z * D + li * 8);
            s16x8 v3 = *(const s16x8*)(xfb + (size_t)ia.w * D + li * 8);
            s16x8 v4 = *(const s16x8*)(xfb + (size_t)ib.x * D + li * 8);
            s16x8 v5 = *(const s16x8*)(xfb + (size_t)ib.y * D + li * 8);
            s16x8 v6 = *(const s16x8*)(xfb + (size_t)ib.z * D + li * 8);
            s16x8 v7 = *(const s16x8*)(xfb + (size_t)ib.w * D + li * 8);
#pragma unroll
            for (int k2 = 0; k2 < 8; ++k2) {
                t[rr][k2] += b2f((unsigned short)v0[k2]);
                t[rr][k2] += b2f((unsigned short)v1[k2]);
                t[rr][k2] += b2f((unsigned short)v2[k2]);
                t[rr][k2] += b2f((unsigned short)v3[k2]);
                t[rr][k2] += b2f((unsigned short)v4[k2]);
                t[rr][k2] += b2f((unsigned short)v5[k2]);
                t[rr][k2] += b2f((unsigned short)v6[k2]);
                t[rr][k2] += b2f((unsigned short)v7[k2]);
            }
        }
    }

#pragma unroll
    for (int rr = 0; rr < 4; ++rr) {
        float rc = 1.0f / (float)(degs[rr] > 0 ? degs[rr] : 1);
        s16x8 o;
#pragma unroll
        for (int k2 = 0; k2 < 8; ++k2) o[k2] = (short)f2b(t[rr][k2] * rc);
        *(s16x8*)(agg + (wv * 16 + rr * 4 + q) * LDSPITCH + li * 8) = o;
    }
    // no __syncthreads: each wave writes and reads only its own 16 LDS rows

    int arow = wrow0 + li; if (arow > N - 1) arow = N - 1;

    f32x4 acc[8];
#pragma unroll
    for (int nt = 0; nt < 8; ++nt) acc[nt] = (f32x4){0.f, 0.f, 0.f, 0.f};

    // phase A: agg @ lin_l  (A-fragments straight from bf16 LDS)
#pragma unroll
    for (int ks = 0; ks < 4; ++ks) {
        s16x8 af = *(const s16x8*)(agg + (wv * 16 + li) * LDSPITCH + ks * 32 + q * 8);
#pragma unroll
        for (int nt = 0; nt < 8; ++nt) {
            s16x8 bf = *(const s16x8*)(Btl + (size_t)(nt * 16 + li) * D + ks * 32 + q * 8);
            acc[nt] = __builtin_amdgcn_mfma_f32_16x16x32_bf16(af, bf, acc[nt], 0, 0, 0);
        }
    }
    // phase B: xf @ lin_r
#pragma unroll
    for (int ks = 0; ks < 4; ++ks) {
        s16x8 af = *(const s16x8*)(xfb + (size_t)arow * D + ks * 32 + q * 8);
#pragma unroll
        for (int nt = 0; nt < 8; ++nt) {
            s16x8 bf = *(const s16x8*)(Btr + (size_t)(nt * 16 + li) * D + ks * 32 + q * 8);
            acc[nt] = __builtin_amdgcn_mfma_f32_16x16x32_bf16(af, bf, acc[nt], 0, 0, 0);
        }
    }

    float a = scal[0], c0 = scal[1];
    float sdot[4] = {0.f, 0.f, 0.f, 0.f};
#pragma unroll
    for (int nt = 0; nt < 8; ++nt) {
        int n = nt * 16 + li;
        float bias = lin_l_b[n];
        float shw = sh_w[n];
#pragma unroll
        for (int r = 0; r < 4; ++r) {
            float t2 = acc[nt][r] + bias;
            sdot[r] += fmaxf(t2, 0.f) * shw;
        }
    }
#pragma unroll
    for (int r = 0; r < 4; ++r) {
        float s = sdot[r];
        s += __shfl_xor(s, 1, 64);
        s += __shfl_xor(s, 2, 64);
        s += __shfl_xor(s, 4, 64);
        s += __shfl_xor(s, 8, 64);
        if (li == 0) {
            int rr = wrow0 + q * 4 + r;
            if (rr < N) out[rr] = a * rer[rr] + (1.f - a) * (c0 + d1[rr] + s);
        }
    }
}

extern "C" void kernel_launch(void* const* d_in, const int* in_sizes, int n_in,
                              void* d_out, int out_size, void* d_ws, size_t ws_size,
                              hipStream_t stream) {
    const float* x        = (const float*)d_in[0];
    const int*   positions= (const int*)d_in[1];
    const int*   lengths  = (const int*)d_in[2];
    const int*   ei       = (const int*)d_in[3];
    const float* rer      = (const float*)d_in[4];
    const float* fp_w     = (const float*)d_in[5];
    const float* fp_b     = (const float*)d_in[6];
    const float* lin_l_w  = (const float*)d_in[7];
    const float* lin_l_b  = (const float*)d_in[8];
    const float* lin_r_w  = (const float*)d_in[9];
    const float* res_w    = (const float*)d_in[10];
    const float* res_b    = (const float*)d_in[11];
    const float* sh_w     = (const float*)d_in[12];
    const float* sh_b     = (const float*)d_in[13];
    const float* alpha    = (const float*)d_in[14];
    int N = in_sizes[1];
    int E = in_sizes[3] / 2;
    float* out = (float*)d_out;

    char* ws = (char*)d_ws;
    size_t off = 0;
    auto alloc = [&](size_t bytes) -> void* {
        void* p = ws + off;
        off = (off + bytes + 255) & ~(size_t)255;
        return p;
    };
    unsigned short* xb  = (unsigned short*)alloc((size_t)(N + 1) * D * 2);  // +1 sentinel zero row
    int* srcs    = (int*)alloc((size_t)N * CAP * 4);
    int* cursor  = (int*)alloc((size_t)N * 4);
    float* d1    = (float*)alloc((size_t)N * 4);
    unsigned short* Btf = (unsigned short*)alloc(D * D * 2);
    unsigned short* Btl = (unsigned short*)alloc(D * D * 2);
    unsigned short* Btr = (unsigned short*)alloc(D * D * 2);
    float* c1    = (float*)alloc(D * 4);
    float* scal  = (float*)alloc(16);

    int mb = (N + 63) / 64;
    int cb = (E + 255) / 256;
    int zb = (N + 1023) / 1024;           // cursor-zero blocks (int4/thread)
    int sb = (N * CAP / 4 + 255) / 256;   // srcs-sentinel blocks (int4/thread)

    k_prep<<<193 + zb + sb, 256, 0, stream>>>(fp_w, lin_l_w, lin_r_w, Btf, Btl, Btr,
                                              res_w, res_b, sh_w, sh_b, alpha, c1, scal,
                                              cursor, srcs, xb, N, zb);
    k_gemm1<<<mb + cb, 256, 0, stream>>>(x, xb, positions, lengths, Btf, fp_w, fp_b,
                                         c1, d1, N, mb, ei, cursor, srcs, E);
    k_gemm2<<<mb, 256, 0, stream>>>(xb, cursor, srcs, Btl, Btr, lin_l_b, sh_w, rer, d1, scal, out, N);
}

// Round 8
// 250.998 us; speedup vs baseline: 1.0364x; 1.0364x over previous
//
#include <hip/hip_runtime.h>
#include <hip/hip_bf16.h>
#include <cstdint>

#define D 128
#define LDSPITCH 136   // shorts; 272B row stride: 16B-aligned, banks uniform
#define CAP 32         // bucket capacity/row (Poisson(6): P(>32) ~ 1e-13)

typedef __attribute__((ext_vector_type(4))) float f32x4;
typedef __attribute__((ext_vector_type(2))) float f32x2;
typedef __attribute__((ext_vector_type(8))) short s16x8;

__device__ __forceinline__ unsigned short f2b(float f) {
    union { float f; uint32_t u; } v; v.f = f;
    uint32_t b = v.u + 0x7fffu + ((v.u >> 16) & 1u);   // RNE
    return (unsigned short)(b >> 16);
}
__device__ __forceinline__ float b2f(unsigned short u) {
    union { uint32_t u; float f; } v; v.u = ((uint32_t)u) << 16; return v.f;
}

// ---- fp8 e4m3fn encode/decode (HW path on gfx950, SW fallback)
#if __has_builtin(__builtin_amdgcn_cvt_pk_fp8_f32) && __has_builtin(__builtin_amdgcn_cvt_pk_f32_fp8)
#define FP8_HW 1
__device__ __forceinline__ unsigned char f_to_fp8(float f) {
    int r = __builtin_amdgcn_cvt_pk_fp8_f32(f, 0.f, 0, false);
    return (unsigned char)(r & 0xff);
}
__device__ __forceinline__ void fp8x8_acc(float* t, int wx, int wy) {
    f32x2 p0 = __builtin_amdgcn_cvt_pk_f32_fp8(wx, false);
    f32x2 p1 = __builtin_amdgcn_cvt_pk_f32_fp8(wx, true);
    f32x2 p2 = __builtin_amdgcn_cvt_pk_f32_fp8(wy, false);
    f32x2 p3 = __builtin_amdgcn_cvt_pk_f32_fp8(wy, true);
    t[0] += p0.x; t[1] += p0.y; t[2] += p1.x; t[3] += p1.y;
    t[4] += p2.x; t[5] += p2.y; t[6] += p3.x; t[7] += p3.y;
}
#else
__device__ __forceinline__ unsigned char f_to_fp8(float f) {
    union { float f; uint32_t u; } v; v.f = f;
    uint32_t s = (v.u >> 31) << 7;
    uint32_t bits = v.u & 0x7fffffffu;
    if (bits < 0x3a800000u) return (unsigned char)s;          // <2^-10 -> 0
    uint32_t r = bits + 0x7ffffu + ((bits >> 20) & 1u);       // RNE @ 3 mantissa bits
    int ee = (int)(r >> 23) - 127 + 7;
    uint32_t man = (r >> 20) & 7u;
    if (ee <= 0) return (unsigned char)s;
    if (ee > 15) { ee = 15; man = 6; }
    if (ee == 15 && man == 7) man = 6;
    return (unsigned char)(s | ((uint32_t)ee << 3) | man);
}
__device__ __forceinline__ float fp8_one(unsigned char u) {
    int s = u >> 7, e = (u >> 3) & 15, m = u & 7;
    if (e == 0) { float v = (float)m * 0.001953125f; return s ? -v : v; }
    union { uint32_t u; float f; } w;
    w.u = ((uint32_t)s << 31) | ((uint32_t)(e + 120) << 23) | ((uint32_t)m << 20);
    return w.f;
}
__device__ __forceinline__ void fp8x8_acc(float* t, int wx, int wy) {
    uint32_t a = (uint32_t)wx, b = (uint32_t)wy;
#pragma unroll
    for (int k = 0; k < 4; ++k) t[k] += fp8_one((a >> (8 * k)) & 0xff);
#pragma unroll
    for (int k = 0; k < 4; ++k) t[4 + k] += fp8_one((b >> (8 * k)) & 0xff);
}
#endif

// ---- prep: [0,192) transpose+bf16 weights; 192: consts + zero sentinel rows;
//            [193,193+zb): zero cursor; [193+zb,..): fill srcs with sentinel N
__global__ __launch_bounds__(256) void k_prep(
    const float* __restrict__ fp_w, const float* __restrict__ lin_l_w,
    const float* __restrict__ lin_r_w,
    unsigned short* __restrict__ Btf, unsigned short* __restrict__ Btl,
    unsigned short* __restrict__ Btr,
    const float* __restrict__ res_w, const float* __restrict__ res_b,
    const float* __restrict__ sh_w, const float* __restrict__ sh_b,
    const float* __restrict__ alpha, float* __restrict__ c1, float* __restrict__ scal,
    int* __restrict__ cursor, int* __restrict__ srcs,
    unsigned short* __restrict__ xb, unsigned char* __restrict__ xf8,
    int N, int zb) {
    int bid = blockIdx.x, tid = threadIdx.x;
    if (bid < 192) {
        int m = bid >> 6;
        int i = (bid & 63) * 256 + tid;
        const float* src = (m == 0) ? fp_w : (m == 1) ? lin_l_w : lin_r_w;
        unsigned short* dst = (m == 0) ? Btf : (m == 1) ? Btl : Btr;
        int k = i >> 7, n = i & 127;
        dst[n * D + k] = f2b(src[k * D + n]);
    } else if (bid == 192) {
        if (tid < 128) {
            float s = 0.f;
            for (int j = 0; j < D; ++j) s += res_w[tid * D + j] * sh_w[j];
            c1[tid] = s;
            if (tid == 0) {
                float c0 = 0.f;
                for (int j = 0; j < D; ++j) c0 += res_b[j] * sh_w[j];
                c0 += sh_b[0];
                float a = 1.f / (1.f + expf(-alpha[0]));
                scal[0] = a; scal[1] = c0;
            }
        } else if (tid < 192) {
            ((unsigned int*)(xb + (size_t)N * D))[tid - 128] = 0u;   // bf16 sentinel row
        } else if (tid < 224) {
            ((unsigned int*)(xf8 + (size_t)N * D))[tid - 192] = 0u;  // fp8 sentinel row
        }
    } else if (bid < 193 + zb) {
        int i = ((bid - 193) * 256 + tid) * 4;
        if (i < N) {
            if (i + 3 < N) *(int4*)(cursor + i) = (int4){0, 0, 0, 0};
            else { for (int k = i; k < N; ++k) cursor[k] = 0; }
        }
    } else {
        int i = ((bid - 193 - zb) * 256 + tid) * 4;
        if (i < N * CAP) *(int4*)(srcs + i) = (int4){N, N, N, N};
    }
}

// ---- GEMM1 (+ bucket fill piggy-backed):
// blocks [0,mb): xf = [x|pos|len] @ fp_w + fp_b -> bf16 xb AND fp8 xf8; d1 = xf.c1
// blocks [mb,..): cursor[dst]++ + srcs[dst*CAP+pos] = src
__global__ __launch_bounds__(256) void k_gemm1(
    const float* __restrict__ x, unsigned short* __restrict__ xb,
    unsigned char* __restrict__ xf8,
    const int* __restrict__ positions, const int* __restrict__ lengths,
    const unsigned short* __restrict__ Btf,
    const float* __restrict__ fp_w, const float* __restrict__ fp_b,
    const float* __restrict__ c1, float* __restrict__ d1, int N, int mb,
    const int* __restrict__ ei, int* __restrict__ cursor, int* __restrict__ srcs, int E) {
    if (blockIdx.x >= mb) {
        int e = (blockIdx.x - mb) * 256 + threadIdx.x;
        if (e < E) {
            int src = ei[e];
            int dst = ei[E + e];
            int pos = atomicAdd(&cursor[dst], 1);
            if (pos < CAP) srcs[dst * CAP + pos] = src;
        }
        return;
    }
    int lane = threadIdx.x & 63;
    int wv = threadIdx.x >> 6;
    int col = lane & 15, q = lane >> 4;
    int row0 = blockIdx.x * 64 + wv * 16;
    int arow = row0 + col; if (arow > N - 1) arow = N - 1;

    f32x4 acc[8];
#pragma unroll
    for (int nt = 0; nt < 8; ++nt) acc[nt] = (f32x4){0.f, 0.f, 0.f, 0.f};

#pragma unroll
    for (int ks = 0; ks < 4; ++ks) {
        const float* xp = x + (size_t)arow * D + ks * 32 + q * 8;
        float4 a0 = *(const float4*)xp;
        float4 a1 = *(const float4*)(xp + 4);
        s16x8 af;
        af[0] = (short)f2b(a0.x); af[1] = (short)f2b(a0.y);
        af[2] = (short)f2b(a0.z); af[3] = (short)f2b(a0.w);
        af[4] = (short)f2b(a1.x); af[5] = (short)f2b(a1.y);
        af[6] = (short)f2b(a1.z); af[7] = (short)f2b(a1.w);
#pragma unroll
        for (int nt = 0; nt < 8; ++nt) {
            s16x8 bf = *(const s16x8*)(Btf + (size_t)(nt * 16 + col) * D + ks * 32 + q * 8);
            acc[nt] = __builtin_amdgcn_mfma_f32_16x16x32_bf16(af, bf, acc[nt], 0, 0, 0);
        }
    }

    float pf[4], lf[4];
#pragma unroll
    for (int r = 0; r < 4; ++r) {
        int rr = row0 + q * 4 + r; int rc = rr < N ? rr : N - 1;
        pf[r] = (float)positions[rc] * (1.0f / 50.0f);
        lf[r] = (float)lengths[rc] * (1.0f / 500.0f);
    }
    float sdot[4] = {0.f, 0.f, 0.f, 0.f};
#pragma unroll
    for (int nt = 0; nt < 8; ++nt) {
        int n = nt * 16 + col;
        float bias = fp_b[n];
        float w128 = fp_w[128 * D + n];
        float w129 = fp_w[129 * D + n];
        float c1v = c1[n];
#pragma unroll
        for (int r = 0; r < 4; ++r) {
            float t = acc[nt][r] + bias + pf[r] * w128 + lf[r] * w129;
            int rr = row0 + q * 4 + r;
            if (rr < N) {
                xb[(size_t)rr * D + n] = f2b(t);
                xf8[(size_t)rr * D + n] = f_to_fp8(t);
            }
            sdot[r] += t * c1v;
        }
    }
#pragma unroll
    for (int r = 0; r < 4; ++r) {
        float s = sdot[r];
        s += __shfl_xor(s, 1, 64);
        s += __shfl_xor(s, 2, 64);
        s += __shfl_xor(s, 4, 64);
        s += __shfl_xor(s, 8, 64);
        if (col == 0) {
            int rr = row0 + q * 4 + r;
            if (rr < N) d1[rr] = s;
        }
    }
}

// ---- GEMM2 fused with bucket mean-gather over fp8 rows (128B = 1 line each).
// Sentinel-padded buckets -> unconditional gathers; wave-uniform round count.
__global__ __launch_bounds__(256) void k_gemm2(
    const unsigned short* __restrict__ xfb, const unsigned char* __restrict__ xf8,
    const int* __restrict__ cursor, const int* __restrict__ srcs,
    const unsigned short* __restrict__ Btl, const unsigned short* __restrict__ Btr,
    const float* __restrict__ lin_l_b, const float* __restrict__ sh_w,
    const float* __restrict__ rer, const float* __restrict__ d1,
    const float* __restrict__ scal, float* __restrict__ out, int N) {
    __shared__ unsigned short agg[64 * LDSPITCH];
    int lane = threadIdx.x & 63;
    int wv = threadIdx.x >> 6;
    int li = lane & 15, q = lane >> 4;
    int wrow0 = blockIdx.x * 64 + wv * 16;

    int degs[4];
    const int* sp[4];
#pragma unroll
    for (int rr = 0; rr < 4; ++rr) {
        int row = wrow0 + rr * 4 + q;
        int ok = row < N;
        int dg = ok ? cursor[row] : 0;
        degs[rr] = dg > CAP ? CAP : dg;
        sp[rr] = srcs + (size_t)(ok ? row : 0) * CAP;
    }
    int dmax = degs[0] > degs[1] ? degs[0] : degs[1];
    if (degs[2] > dmax) dmax = degs[2];
    if (degs[3] > dmax) dmax = degs[3];
    dmax = max(dmax, __shfl_xor(dmax, 16, 64));
    dmax = max(dmax, __shfl_xor(dmax, 32, 64));
    int rounds = (dmax + 7) >> 3;

    float t[4][8];
#pragma unroll
    for (int rr = 0; rr < 4; ++rr)
#pragma unroll
        for (int k2 = 0; k2 < 8; ++k2) t[rr][k2] = 0.f;

    for (int jr = 0; jr < rounds; ++jr) {
        int j = jr * 8;
#pragma unroll
        for (int rr = 0; rr < 4; ++rr) {
            int4 ia = *(const int4*)(sp[rr] + j);
            int4 ib = *(const int4*)(sp[rr] + j + 4);
            int2 v0 = *(const int2*)(xf8 + (size_t)ia.x * D + li * 8);
            int2 v1 = *(const int2*)(xf8 + (size_t)ia.y * D + li * 8);
            int2 v2 = *(const int2*)(xf8 + (size_t)ia.z * D + li * 8);
            int2 v3 = *(const int2*)(xf8 + (size_t)ia.w * D + li * 8);
            int2 v4 = *(const int2*)(xf8 + (size_t)ib.x * D + li * 8);
            int2 v5 = *(const int2*)(xf8 + (size_t)ib.y * D + li * 8);
            int2 v6 = *(const int2*)(xf8 + (size_t)ib.z * D + li * 8);
            int2 v7 = *(const int2*)(xf8 + (size_t)ib.w * D + li * 8);
            fp8x8_acc(t[rr], v0.x, v0.y);
            fp8x8_acc(t[rr], v1.x, v1.y);
            fp8x8_acc(t[rr], v2.x, v2.y);
            fp8x8_acc(t[rr], v3.x, v3.y);
            fp8x8_acc(t[rr], v4.x, v4.y);
            fp8x8_acc(t[rr], v5.x, v5.y);
            fp8x8_acc(t[rr], v6.x, v6.y);
            fp8x8_acc(t[rr], v7.x, v7.y);
        }
    }

#pragma unroll
    for (int rr = 0; rr < 4; ++rr) {
        float rc = 1.0f / (float)(degs[rr] > 0 ? degs[rr] : 1);
        s16x8 o;
#pragma unroll
        for (int k2 = 0; k2 < 8; ++k2) o[k2] = (short)f2b(t[rr][k2] * rc);
        *(s16x8*)(agg + (wv * 16 + rr * 4 + q) * LDSPITCH + li * 8) = o;
    }
    // no __syncthreads: each wave writes and reads only its own 16 LDS rows

    int arow = wrow0 + li; if (arow > N - 1) arow = N - 1;

    f32x4 acc[8];
#pragma unroll
    for (int nt = 0; nt < 8; ++nt) acc[nt] = (f32x4){0.f, 0.f, 0.f, 0.f};

    // phase A: agg @ lin_l  (A-fragments straight from bf16 LDS)
#pragma unroll
    for (int ks = 0; ks < 4; ++ks) {
        s16x8 af = *(const s16x8*)(agg + (wv * 16 + li) * LDSPITCH + ks * 32 + q * 8);
#pragma unroll
        for (int nt = 0; nt < 8; ++nt) {
            s16x8 bf = *(const s16x8*)(Btl + (size_t)(nt * 16 + li) * D + ks * 32 + q * 8);
            acc[nt] = __builtin_amdgcn_mfma_f32_16x16x32_bf16(af, bf, acc[nt], 0, 0, 0);
        }
    }
    // phase B: xf @ lin_r  (bf16, exact self term)
#pragma unroll
    for (int ks = 0; ks < 4; ++ks) {
        s16x8 af = *(const s16x8*)(xfb + (size_t)arow * D + ks * 32 + q * 8);
#pragma unroll
        for (int nt = 0; nt < 8; ++nt) {
            s16x8 bf = *(const s16x8*)(Btr + (size_t)(nt * 16 + li) * D + ks * 32 + q * 8);
            acc[nt] = __builtin_amdgcn_mfma_f32_16x16x32_bf16(af, bf, acc[nt], 0, 0, 0);
        }
    }

    float a = scal[0], c0 = scal[1];
    float sdot[4] = {0.f, 0.f, 0.f, 0.f};
#pragma unroll
    for (int nt = 0; nt < 8; ++nt) {
        int n = nt * 16 + li;
        float bias = lin_l_b[n];
        float shw = sh_w[n];
#pragma unroll
        for (int r = 0; r < 4; ++r) {
            float t2 = acc[nt][r] + bias;
            sdot[r] += fmaxf(t2, 0.f) * shw;
        }
    }
#pragma unroll
    for (int r = 0; r < 4; ++r) {
        float s = sdot[r];
        s += __shfl_xor(s, 1, 64);
        s += __shfl_xor(s, 2, 64);
        s += __shfl_xor(s, 4, 64);
        s += __shfl_xor(s, 8, 64);
        if (li == 0) {
            int rr = wrow0 + q * 4 + r;
            if (rr < N) out[rr] = a * rer[rr] + (1.f - a) * (c0 + d1[rr] + s);
        }
    }
}

extern "C" void kernel_launch(void* const* d_in, const int* in_sizes, int n_in,
                              void* d_out, int out_size, void* d_ws, size_t ws_size,
                              hipStream_t stream) {
    const float* x        = (const float*)d_in[0];
    const int*   positions= (const int*)d_in[1];
    const int*   lengths  = (const int*)d_in[2];
    const int*   ei       = (const int*)d_in[3];
    const float* rer      = (const float*)d_in[4];
    const float* fp_w     = (const float*)d_in[5];
    const float* fp_b     = (const float*)d_in[6];
    const float* lin_l_w  = (const float*)d_in[7];
    const float* lin_l_b  = (const float*)d_in[8];
    const float* lin_r_w  = (const float*)d_in[9];
    const float* res_w    = (const float*)d_in[10];
    const float* res_b    = (const float*)d_in[11];
    const float* sh_w     = (const float*)d_in[12];
    const float* sh_b     = (const float*)d_in[13];
    const float* alpha    = (const float*)d_in[14];
    int N = in_sizes[1];
    int E = in_sizes[3] / 2;
    float* out = (float*)d_out;

    char* ws = (char*)d_ws;
    size_t off = 0;
    auto alloc = [&](size_t bytes) -> void* {
        void* p = ws + off;
        off = (off + bytes + 255) & ~(size_t)255;
        return p;
    };
    unsigned short* xb  = (unsigned short*)alloc((size_t)(N + 1) * D * 2);  // +sentinel row
    unsigned char*  xf8 = (unsigned char*)alloc((size_t)(N + 1) * D);       // fp8 copy +sentinel
    int* srcs    = (int*)alloc((size_t)N * CAP * 4);
    int* cursor  = (int*)alloc((size_t)N * 4);
    float* d1    = (float*)alloc((size_t)N * 4);
    unsigned short* Btf = (unsigned short*)alloc(D * D * 2);
    unsigned short* Btl = (unsigned short*)alloc(D * D * 2);
    unsigned short* Btr = (unsigned short*)alloc(D * D * 2);
    float* c1    = (float*)alloc(D * 4);
    float* scal  = (float*)alloc(16);

    int mb = (N + 63) / 64;
    int cb = (E + 255) / 256;
    int zb = (N + 1023) / 1024;           // cursor-zero blocks
    int sb = (N * CAP / 4 + 255) / 256;   // srcs-sentinel blocks

    k_prep<<<193 + zb + sb, 256, 0, stream>>>(fp_w, lin_l_w, lin_r_w, Btf, Btl, Btr,
                                              res_w, res_b, sh_w, sh_b, alpha, c1, scal,
                                              cursor, srcs, xb, xf8, N, zb);
    k_gemm1<<<mb + cb, 256, 0, stream>>>(x, xb, xf8, positions, lengths, Btf, fp_w, fp_b,
                                         c1, d1, N, mb, ei, cursor, srcs, E);
    k_gemm2<<<mb, 256, 0, stream>>>(xb, xf8, cursor, srcs, Btl, Btr, lin_l_b, sh_w,
                                    rer, d1, scal, out, N);
}